// Round 15
// baseline (81.846 us; speedup 1.0000x reference)
//
#include <hip/hip_runtime.h>

typedef __bf16 bf16x8 __attribute__((ext_vector_type(8)));
typedef __bf16 bf16x2 __attribute__((ext_vector_type(2)));
typedef float  f32x4  __attribute__((ext_vector_type(4)));

// ws layout (bytes). All A-operand fragments lane-linear:
// one frag = 1024 B; lane l's 16 B at frag_base + l*16 (coalesced dwordx4).
//   WT0 : 8 frags   (nt 0..7, K=32 zero-padded)      [0      .. 8191  ]
//   WTH : 160 frags ((h*4+ks)*8 + nt)                [8192   .. 172031]
//   WLT : 8 frags   (ks 0..3 real, 4..7 zero pad)    [172032 .. 180223]
#define WS_WT0_B 0
#define WS_WTH_B 8192
#define WS_WLT_B 172032

__device__ __forceinline__ unsigned short f2b(float f) {
  return __builtin_bit_cast(unsigned short, (__bf16)f);
}

__global__ void prep_kernel(const float* __restrict__ W0,
                            const float* __restrict__ Wh,
                            const float* __restrict__ WL,
                            unsigned short* __restrict__ ws) {
  int i = blockIdx.x * 256 + threadIdx.x;   // ushort index == byte/2
  int l  = (i >> 3) & 63;                   // lane within frag
  int j  = i & 7;                           // element within lane's 8
  int lm = l & 15, lh = l >> 4;
  if (i < 4096) {                           // WT0
    int nt = i >> 9;
    int n = nt * 16 + lm, k = lh * 8 + j;
    ws[i] = f2b(k < 4 ? W0[k * 128 + n] : 0.f);
  } else if (i < 86016) {                   // WTH
    int t = i - 4096;
    int frag = t >> 9;                      // (h*4+ks)*8 + nt
    int nt = frag & 7, ks = (frag >> 3) & 3, h = frag >> 5;
    int n = nt * 16 + lm, k = ks * 32 + lh * 8 + j;
    ws[i] = f2b(Wh[(h * 128 + k) * 128 + n]);
  } else if (i < 90112) {                   // WLT (8 frags, 4 real + 4 zero)
    int t = i - 86016;
    int f = t >> 9;
    int k = (f & 3) * 32 + lh * 8 + j;
    ws[i] = f2b((f < 4 && lm < 2) ? WL[k * 2 + lm] : 0.f);
  }
}

// swish via exp2: u = z * -log2(e), e = 2^u, s = rcp(1+e), z*s.
__device__ __forceinline__ f32x4 swish4(f32x4 z) {
  const f32x4 u = z * (-1.44269504088896340736f);
  f32x4 e;
#if __has_builtin(__builtin_amdgcn_exp2f)
  e[0] = __builtin_amdgcn_exp2f(u[0]); e[1] = __builtin_amdgcn_exp2f(u[1]);
  e[2] = __builtin_amdgcn_exp2f(u[2]); e[3] = __builtin_amdgcn_exp2f(u[3]);
#else
  e[0] = __expf(u[0] * 0.6931471805599453f); e[1] = __expf(u[1] * 0.6931471805599453f);
  e[2] = __expf(u[2] * 0.6931471805599453f); e[3] = __expf(u[3] * 0.6931471805599453f);
#endif
  const f32x4 w = e + 1.f;
  f32x4 s;
  s[0] = __builtin_amdgcn_rcpf(w[0]); s[1] = __builtin_amdgcn_rcpf(w[1]);
  s[2] = __builtin_amdgcn_rcpf(w[2]); s[3] = __builtin_amdgcn_rcpf(w[3]);
  return z * s;
}

__device__ __forceinline__ uint2 pack4(f32x4 r) {   // v_cvt_pk_bf16_f32 path
  bf16x2 lo = {(__bf16)r[0], (__bf16)r[1]};
  bf16x2 hi = {(__bf16)r[2], (__bf16)r[3]};
  uint2 wv;
  wv.x = __builtin_bit_cast(unsigned int, lo);
  wv.y = __builtin_bit_cast(unsigned int, hi);
  return wv;
}

#define LRD(addr) __builtin_bit_cast(bf16x8, *reinterpret_cast<const uint4*>(addr))
#define MFMA(a, b, c) __builtin_amdgcn_mfma_f32_16x16x32_bf16((a), (b), (c), 0, 0, 0)
#define SB() __builtin_amdgcn_sched_barrier(0)
#define WAITVM(N) asm volatile("s_waitcnt vmcnt(" #N ")" ::: "memory")
#define WAITLGKM() asm volatile("s_waitcnt lgkmcnt(0)" ::: "memory")
// light barrier: NO vmcnt drain; sched_barrier on BOTH sides.
#define LBAR() do { SB(); __builtin_amdgcn_s_barrier(); SB(); } while (0)

// Cooperative 8KB stage: 256 threads x 2 x 16B direct global->LDS (2 vm ops/wave).
// Wave w writes frags {w, 4+w}; consumers read other waves' frags -> the
// counted vmcnt wait MUST be before a barrier (see below), not before a read.
__device__ __forceinline__ void stage8k(const char* src, char* dst, int tid) {
  const int woff = (tid >> 6) * 1024;    // wave-uniform LDS base
#if __has_builtin(__builtin_amdgcn_global_load_lds)
  __builtin_amdgcn_global_load_lds(
      (const __attribute__((address_space(1))) unsigned int*)(src + tid * 16),
      (__attribute__((address_space(3))) unsigned int*)(dst + woff), 16, 0, 0);
  __builtin_amdgcn_global_load_lds(
      (const __attribute__((address_space(1))) unsigned int*)(src + 4096 + tid * 16),
      (__attribute__((address_space(3))) unsigned int*)(dst + 4096 + woff), 16, 0, 0);
#else
  const uint4 v0 = *reinterpret_cast<const uint4*>(src + tid * 16);
  const uint4 v1 = *reinterpret_cast<const uint4*>(src + 4096 + tid * 16);
  *reinterpret_cast<uint4*>(dst + tid * 16) = v0;
  *reinterpret_cast<uint4*>(dst + 4096 + tid * 16) = v1;
#endif
}

// Channel-split + counted-vmcnt pipeline, RACE FIXED (R14 tripwire):
// vmcnt is per-wave but buffers are consumed cross-wave. The wait is now at
// PHASE END, before the barrier: each wave retires its own stages to depth
// <=4, then the barrier makes that collective, then the next phase may read
// the buffer staged 3 phases ago (m201 pattern: "vmcnt(N); s_barrier").
// Schedule: phase (h,ks) reads wb[(1+ks)&3], stages into wb[ks]; ends with
// WAITVM(4); LBAR. End of phase i: stages {i-2,i-1,i} outstanding (6 ops),
// vmcnt(4) retires stage i-2; phase i+1 reads stage i-2's buffer. WAR on
// wb[ks] (read one phase earlier) is ordered by lgkmcnt waits pre-barrier.
__launch_bounds__(256, 3)
__global__ void mlp_kernel(const float* __restrict__ X,
                           const float* __restrict__ nu_min_p,
                           const float* __restrict__ nu_max_p,
                           const float* __restrict__ b0,
                           const float* __restrict__ bh,
                           const float* __restrict__ bL,
                           const unsigned short* __restrict__ ws,
                           float* __restrict__ out) {
  __shared__ __align__(16) char smem[16384 + 4 * 8192 + 2560];
  char* Hs  = smem;                        // [64 pt][128 ch] bf16, swizzled
  char* wb[4] = { smem + 16384, smem + 24576, smem + 32768, smem + 40960 };
  float* bias_lds = reinterpret_cast<float*>(smem + 49152);
  const int tid  = threadIdx.x;
  const int lane = tid & 63, wave = tid >> 6;
  const int lm = lane & 15, lh = lane >> 4;
  const int row0 = blockIdx.x * 64;
  const char* wsb = reinterpret_cast<const char*>(ws);
  const int xorm = (lm & 7) << 4;
  const int ntb = wave * 2;                // this wave's first nt
  int vaG[4], waG[4];
#pragma unroll
  for (int g = 0; g < 4; ++g) {
    vaG[g] = (g * 16 + lm) * 256 + ((lh * 16) ^ xorm);
    waG[g] = (g * 16 + lm) * 256 + (((lh * 8) ^ xorm) ^ (wave << 6));
  }

  // ---- prologue: inputs, bias cache, stage s0(WT0)->wb0, s1->wb1, s2->wb2 ----
#pragma unroll
  for (int i = 0; i < 3; ++i) {
    const int idx = i * 256 + tid;
    if (idx < 640) bias_lds[idx] = bh[idx];
  }
  if (tid < 64) {
    const float4 xv = reinterpret_cast<const float4*>(X)[row0 + tid];
    const float numin = nu_min_p[0], numax = nu_max_p[0];
    const float v0 = xv.x;
    const float v1 = xv.y;
    const float v2 = 2.f * xv.z - 1.f;
    const float v3 = 2.f * (xv.w - numin) / (numax - numin) - 1.f;
    uint4 c0;
    c0.x = (unsigned)f2b(v0) | ((unsigned)f2b(v1) << 16);
    c0.y = (unsigned)f2b(v2) | ((unsigned)f2b(v3) << 16);
    c0.z = 0u; c0.w = 0u;
    const uint4 z4 = make_uint4(0u, 0u, 0u, 0u);
    const int xr = (tid & 7) << 4;
    char* rp = Hs + tid * 256;
    *reinterpret_cast<uint4*>(rp + (0  ^ xr)) = c0;
    *reinterpret_cast<uint4*>(rp + (16 ^ xr)) = z4;
    *reinterpret_cast<uint4*>(rp + (32 ^ xr)) = z4;
    *reinterpret_cast<uint4*>(rp + (48 ^ xr)) = z4;
  }
  stage8k(wsb + WS_WT0_B, wb[0], tid);           // s0: L0 weights
  stage8k(wsb + WS_WTH_B, wb[1], tid);           // s1: h0ks0
  stage8k(wsb + WS_WTH_B + 8192, wb[2], tid);    // s2: h0ks1
  __syncthreads();   // full drain; wb0..wb2 valid for every wave

  f32x4 acc[2][4];
  bf16x8 a0, a1;

  // ================= L0 : K=32, read wb0; stage s3(h0ks2)->wb3 =================
  {
    stage8k(wsb + WS_WTH_B + 16384, wb[3], tid);
    a0 = LRD(wb[0] + (ntb + 0) * 1024 + lane * 16);
    a1 = LRD(wb[0] + (ntb + 1) * 1024 + lane * 16);
    const f32x4 bv0 = *reinterpret_cast<const f32x4*>(b0 + (ntb + 0) * 16 + lh * 4);
    const f32x4 bv1 = *reinterpret_cast<const f32x4*>(b0 + (ntb + 1) * 16 + lh * 4);
#pragma unroll
    for (int g = 0; g < 4; ++g) {
      const bf16x8 f = LRD(Hs + vaG[g]);
      acc[0][g] = MFMA(a0, f, bv0);
      acc[1][g] = MFMA(a1, f, bv1);
    }
    WAITLGKM(); LBAR();   // L0 reads of Hs complete everywhere
#pragma unroll
    for (int j = 0; j < 2; ++j)
#pragma unroll
      for (int g = 0; g < 4; ++g) {
        const uint2 wv = pack4(swish4(acc[j][g]));
        *reinterpret_cast<uint2*>(Hs + (waG[g] ^ (j << 5))) = wv;
      }
    WAITLGKM(); LBAR();   // strip writes visible to all waves
  }

  // phase body: stage next source; read A-frags + B-frags; 8 MFMA.
  // (Safety of RBI comes from the PREVIOUS phase's WAITVM(4)+LBAR.)
#define HPHASE(RBI, SBI, SRC, KSOFF, C0, C1)                                 \
  do {                                                                       \
    stage8k((SRC), wb[SBI], tid);                                            \
    a0 = LRD(wb[RBI] + (ntb + 0) * 1024 + lane * 16);                        \
    a1 = LRD(wb[RBI] + (ntb + 1) * 1024 + lane * 16);                        \
    _Pragma("unroll")                                                        \
    for (int g = 0; g < 4; ++g) {                                            \
      const bf16x8 f = LRD(Hs + (vaG[g] ^ (KSOFF)));                         \
      acc[0][g] = MFMA(a0, f, (C0));                                         \
      acc[1][g] = MFMA(a1, f, (C1));                                         \
    }                                                                        \
  } while (0)

  // ============ 5 hidden layers : counted-vmcnt pipelined phases ============
#pragma unroll 1
  for (int h = 0; h < 5; ++h) {
    const char* wsrc = wsb + WS_WTH_B + h * 32768;
    const char* st0 = wsrc + 24576;                                    // (h,ks3)
    const char* st1 = (h < 4) ? (wsrc + 32768)         : (wsb + WS_WLT_B);  // (h+1,ks0)/WLT
    const char* st2 = (h < 4) ? (wsrc + 32768 + 8192)  : (wsb + WS_WT0_B);  // pad
    const char* st3 = (h < 4) ? (wsrc + 32768 + 16384) : (wsb + WS_WT0_B);  // pad
    const f32x4 bv0 = *reinterpret_cast<const f32x4*>(bias_lds + h * 128 + (ntb + 0) * 16 + lh * 4);
    const f32x4 bv1 = *reinterpret_cast<const f32x4*>(bias_lds + h * 128 + (ntb + 1) * 16 + lh * 4);

    HPHASE(1, 0, st0, 0,   bv0, bv1);              // ks0: read wb1, stage->wb0
    WAITVM(4); LBAR();
    HPHASE(2, 1, st1, 64,  acc[0][g], acc[1][g]);  // ks1: read wb2, stage->wb1
    WAITVM(4); LBAR();
    HPHASE(3, 2, st2, 128, acc[0][g], acc[1][g]);  // ks2: read wb3, stage->wb2
    WAITVM(4); LBAR();
    HPHASE(0, 3, st3, 192, acc[0][g], acc[1][g]);  // ks3: read wb0, stage->wb3
    WAITVM(4); WAITLGKM(); LBAR();   // stage h,ks1 landed + ks3 Hs reads done
#pragma unroll
    for (int j = 0; j < 2; ++j)
#pragma unroll
      for (int g = 0; g < 4; ++g) {
        const uint2 wv = pack4(swish4(acc[j][g]));
        *reinterpret_cast<uint2*>(Hs + (waG[g] ^ (j << 5))) = wv;
      }
    WAITLGKM(); LBAR();   // strip writes visible before next-layer reads
  }
#undef HPHASE

  // ========== final layer : [128 -> 2]; weights in wb1 (WLT staged at h4ks1) ==========
  {
    // WLT's stage was retired by the WAITVM(4)+LBAR at end of (h4,ks3).
    const float bl0 = bL[0], bl1 = bL[1];
    const int vaF = (wave * 16 + lm) * 256 + ((lh * 16) ^ xorm);
    f32x4 accL = {0.f, 0.f, 0.f, 0.f};
#pragma unroll
    for (int ks = 0; ks < 4; ++ks) {
      const bf16x8 a = LRD(wb[1] + ks * 1024 + lane * 16);
      const bf16x8 f = LRD(Hs + (vaF ^ (ks << 6)));
      accL = MFMA(a, f, accL);
    }
    if (lh == 0) {
      const int p = wave * 16 + lm;
      float2 o;
      o.x = accL[0] + bl0;
      o.y = accL[1] + bl1;
      *reinterpret_cast<float2*>(out + (size_t)(row0 + p) * 2) = o;
    }
  }
}

extern "C" void kernel_launch(void* const* d_in, const int* in_sizes, int n_in,
                              void* d_out, int out_size, void* d_ws, size_t ws_size,
                              hipStream_t stream) {
  const float* X     = (const float*)d_in[0];
  const float* numin = (const float*)d_in[1];
  const float* numax = (const float*)d_in[2];
  const float* W0    = (const float*)d_in[3];
  const float* b0    = (const float*)d_in[4];
  const float* Wh    = (const float*)d_in[5];
  const float* bh    = (const float*)d_in[6];
  const float* WL    = (const float*)d_in[7];
  const float* bL    = (const float*)d_in[8];
  unsigned short* ws = (unsigned short*)d_ws;
  float* out = (float*)d_out;

  hipLaunchKernelGGL(prep_kernel, dim3(352), dim3(256), 0, stream, W0, Wh, WL, ws);
  hipLaunchKernelGGL(mlp_kernel, dim3(4096), dim3(256), 0, stream,
                     X, numin, numax, b0, bh, bL, ws, out);
}

// Round 16
// 78.522 us; speedup vs baseline: 1.0423x; 1.0423x over previous
//
#include <hip/hip_runtime.h>

typedef __bf16 bf16x8 __attribute__((ext_vector_type(8)));
typedef __bf16 bf16x2 __attribute__((ext_vector_type(2)));
typedef float  f32x4  __attribute__((ext_vector_type(4)));

// ws layout (bytes). All A-operand fragments lane-linear:
// one frag = 1024 B; lane l's 16 B at frag_base + l*16 (coalesced dwordx4).
//   WT0 : 8 frags   (nt 0..7, K=32 zero-padded)      [0      .. 8191  ]
//   WTH : 160 frags ((h*4+ks)*8 + nt)                [8192   .. 172031]
//   WLT : 8 frags   (ks 0..3 real, 4..7 zero pad)    [172032 .. 180223]
#define WS_WT0_B 0
#define WS_WTH_B 8192
#define WS_WLT_B 172032

__device__ __forceinline__ unsigned short f2b(float f) {
  return __builtin_bit_cast(unsigned short, (__bf16)f);
}

__global__ void prep_kernel(const float* __restrict__ W0,
                            const float* __restrict__ Wh,
                            const float* __restrict__ WL,
                            unsigned short* __restrict__ ws) {
  int i = blockIdx.x * 256 + threadIdx.x;   // ushort index == byte/2
  int l  = (i >> 3) & 63;                   // lane within frag
  int j  = i & 7;                           // element within lane's 8
  int lm = l & 15, lh = l >> 4;
  if (i < 4096) {                           // WT0
    int nt = i >> 9;
    int n = nt * 16 + lm, k = lh * 8 + j;
    ws[i] = f2b(k < 4 ? W0[k * 128 + n] : 0.f);
  } else if (i < 86016) {                   // WTH
    int t = i - 4096;
    int frag = t >> 9;                      // (h*4+ks)*8 + nt
    int nt = frag & 7, ks = (frag >> 3) & 3, h = frag >> 5;
    int n = nt * 16 + lm, k = ks * 32 + lh * 8 + j;
    ws[i] = f2b(Wh[(h * 128 + k) * 128 + n]);
  } else if (i < 90112) {                   // WLT (8 frags, 4 real + 4 zero)
    int t = i - 86016;
    int f = t >> 9;
    int k = (f & 3) * 32 + lh * 8 + j;
    ws[i] = f2b((f < 4 && lm < 2) ? WL[k * 2 + lm] : 0.f);
  }
}

// swish via exp2: u = z * -log2(e), e = 2^u, s = rcp(1+e), z*s.
__device__ __forceinline__ f32x4 swish4(f32x4 z) {
  const f32x4 u = z * (-1.44269504088896340736f);
  f32x4 e;
#if __has_builtin(__builtin_amdgcn_exp2f)
  e[0] = __builtin_amdgcn_exp2f(u[0]); e[1] = __builtin_amdgcn_exp2f(u[1]);
  e[2] = __builtin_amdgcn_exp2f(u[2]); e[3] = __builtin_amdgcn_exp2f(u[3]);
#else
  e[0] = __expf(u[0] * 0.6931471805599453f); e[1] = __expf(u[1] * 0.6931471805599453f);
  e[2] = __expf(u[2] * 0.6931471805599453f); e[3] = __expf(u[3] * 0.6931471805599453f);
#endif
  const f32x4 w = e + 1.f;
  f32x4 s;
  s[0] = __builtin_amdgcn_rcpf(w[0]); s[1] = __builtin_amdgcn_rcpf(w[1]);
  s[2] = __builtin_amdgcn_rcpf(w[2]); s[3] = __builtin_amdgcn_rcpf(w[3]);
  return z * s;
}

__device__ __forceinline__ uint2 pack4(f32x4 r) {   // v_cvt_pk_bf16_f32 path
  bf16x2 lo = {(__bf16)r[0], (__bf16)r[1]};
  bf16x2 hi = {(__bf16)r[2], (__bf16)r[3]};
  uint2 wv;
  wv.x = __builtin_bit_cast(unsigned int, lo);
  wv.y = __builtin_bit_cast(unsigned int, hi);
  return wv;
}

#define SB() __builtin_amdgcn_sched_barrier(0)
#define GLD(addr) __builtin_bit_cast(bf16x8, *reinterpret_cast<const uint4*>(addr))
#define LRD(addr) __builtin_bit_cast(bf16x8, *reinterpret_cast<const uint4*>(addr))
#define MFMA(a, b, c) __builtin_amdgcn_mfma_f32_16x16x32_bf16((a), (b), (c), 0, 0, 0)

// One wave per block, 64 POINTS per wave (R7 structure, 2x the ILP):
// acc[8 nt][4 pt] = 128 AGPR; 32 independent MFMAs per phase cover the
// weight-load latency in-wave (TLP is capped at 2-3 waves/SIMD everywhere
// we've measured, so buy ILP instead). Weight stream per point halves.
// SB()-pinned 2-stage pipeline (R7 discipline — never spilled).
// Regs ~240 <= 256 cap at (64,2); LDS 18.9KB -> 8 blocks/CU (reg-capped).
__launch_bounds__(64, 2)
__global__ void mlp_kernel(const float* __restrict__ X,
                           const float* __restrict__ nu_min_p,
                           const float* __restrict__ nu_max_p,
                           const float* __restrict__ b0,
                           const float* __restrict__ bh,
                           const float* __restrict__ bL,
                           const unsigned short* __restrict__ ws,
                           float* __restrict__ out) {
  __shared__ __align__(16) char smem[64 * 256 + 5 * 128 * 4];  // Hs + bias
  char* Hs = smem;
  float* bias_lds = reinterpret_cast<float*>(smem + 16384);
  const int lane = threadIdx.x;
  const int lm = lane & 15, lh = lane >> 4;
  const int row0 = blockIdx.x * 64;
  const char* ap = reinterpret_cast<const char*>(ws) + lane * 16;
  const int xorm = (lm & 7) << 4;
  // rd(pt,ks) = (va0 + pt*4096) ^ (ks<<6); wr(nt,pt) = (wa0 + pt*4096) ^ (nt<<5)
  const int va0 = lm * 256 + ((lh * 16) ^ xorm);
  const int wa0 = lm * 256 + ((lh * 8) ^ xorm);

  // ---- issue L0 weight frags (into aB) + L0 bias + bh staging up front ----
  bf16x8 aA[8], aB[8];
#pragma unroll
  for (int nt = 0; nt < 8; ++nt) aB[nt] = GLD(ap + WS_WT0_B + nt * 1024);
  f32x4 bv0[8];
#pragma unroll
  for (int nt = 0; nt < 8; ++nt)
    bv0[nt] = *reinterpret_cast<const f32x4*>(b0 + nt * 16 + lh * 4);
  float bstg[10];
#pragma unroll
  for (int i = 0; i < 10; ++i) bstg[i] = bh[i * 64 + lane];

  // ---- stage scaled inputs: each lane owns one of the 64 rows ----
  {
    const float4 xv = reinterpret_cast<const float4*>(X)[row0 + lane];
    const float numin = nu_min_p[0], numax = nu_max_p[0];
    const float v0 = xv.x;
    const float v1 = xv.y;
    const float v2 = 2.f * xv.z - 1.f;
    const float v3 = 2.f * (xv.w - numin) / (numax - numin) - 1.f;
    uint4 c0;
    c0.x = (unsigned)f2b(v0) | ((unsigned)f2b(v1) << 16);
    c0.y = (unsigned)f2b(v2) | ((unsigned)f2b(v3) << 16);
    c0.z = 0u; c0.w = 0u;
    const uint4 z4 = make_uint4(0u, 0u, 0u, 0u);
    const int xr = (lane & 7) << 4;
    char* rp = Hs + lane * 256;
    *reinterpret_cast<uint4*>(rp + (0  ^ xr)) = c0;
    *reinterpret_cast<uint4*>(rp + (16 ^ xr)) = z4;
    *reinterpret_cast<uint4*>(rp + (32 ^ xr)) = z4;
    *reinterpret_cast<uint4*>(rp + (48 ^ xr)) = z4;
  }
  // bh -> LDS (consumed by hidden-layer epilogues)
#pragma unroll
  for (int i = 0; i < 10; ++i) bias_lds[i * 64 + lane] = bstg[i];

  f32x4 acc[8][4];
  bf16x8 bfrA[4], bfrB[4];

  // ================= Layer 0 : K = 32, bias as MFMA C-in (aB) =================
#pragma unroll
  for (int pt = 0; pt < 4; ++pt) bfrA[pt] = LRD(Hs + va0 + pt * 4096);
#pragma unroll
  for (int nt = 0; nt < 8; ++nt)
#pragma unroll
    for (int pt = 0; pt < 4; ++pt)
      acc[nt][pt] = MFMA(aB[nt], bfrA[pt], bv0[nt]);
  // preload h=0 ks=0 weight frags into aA (hidden under L0 epilogue)
#pragma unroll
  for (int nt = 0; nt < 8; ++nt) aA[nt] = GLD(ap + WS_WTH_B + nt * 1024);
  // L0 epilogue (bias already in acc)
#pragma unroll
  for (int nt = 0; nt < 8; ++nt)
#pragma unroll
    for (int pt = 0; pt < 4; ++pt) {
      const uint2 wv = pack4(swish4(acc[nt][pt]));
      *reinterpret_cast<uint2*>(Hs + ((wa0 + pt * 4096) ^ (nt << 5))) = wv;
    }

  const f32x4 zero4 = {0.f, 0.f, 0.f, 0.f};

  // ============ 5 hidden layers : SB()-pinned 2-stage pipeline ============
#pragma unroll 1
  for (int h = 0; h < 5; ++h) {
    const char* wb = ap + WS_WTH_B + h * 32768;
    const float* bl = bias_lds + h * 128;

    // phase 0: compute aA/bfrA(ks0); prefetch aB,bfrB <- ks1
#pragma unroll
    for (int pt = 0; pt < 4; ++pt) bfrA[pt] = LRD(Hs + va0 + pt * 4096);
#pragma unroll
    for (int nt = 0; nt < 8; ++nt) aB[nt] = GLD(wb + 8192 + nt * 1024);
#pragma unroll
    for (int pt = 0; pt < 4; ++pt) bfrB[pt] = LRD(Hs + ((va0 + pt * 4096) ^ 64));
#pragma unroll
    for (int nt = 0; nt < 8; ++nt)
#pragma unroll
      for (int pt = 0; pt < 4; ++pt)
        acc[nt][pt] = MFMA(aA[nt], bfrA[pt], zero4);
    SB();
    // phase 1: compute aB/bfrB(ks1); prefetch aA,bfrA <- ks2
#pragma unroll
    for (int nt = 0; nt < 8; ++nt) aA[nt] = GLD(wb + 16384 + nt * 1024);
#pragma unroll
    for (int pt = 0; pt < 4; ++pt) bfrA[pt] = LRD(Hs + ((va0 + pt * 4096) ^ 128));
#pragma unroll
    for (int nt = 0; nt < 8; ++nt)
#pragma unroll
      for (int pt = 0; pt < 4; ++pt)
        acc[nt][pt] = MFMA(aB[nt], bfrB[pt], acc[nt][pt]);
    SB();
    // phase 2: compute aA/bfrA(ks2); prefetch aB,bfrB <- ks3
#pragma unroll
    for (int nt = 0; nt < 8; ++nt) aB[nt] = GLD(wb + 24576 + nt * 1024);
#pragma unroll
    for (int pt = 0; pt < 4; ++pt) bfrB[pt] = LRD(Hs + ((va0 + pt * 4096) ^ 192));
#pragma unroll
    for (int nt = 0; nt < 8; ++nt)
#pragma unroll
      for (int pt = 0; pt < 4; ++pt)
        acc[nt][pt] = MFMA(aA[nt], bfrA[pt], acc[nt][pt]);
    SB();
    // phase 3: compute aB/bfrB(ks3); prefetch aA <- next ks0 (continuous
    // stream: at h=4 this lands on WLT -> final-layer weights in registers)
#pragma unroll
    for (int nt = 0; nt < 8; ++nt) aA[nt] = GLD(wb + 32768 + nt * 1024);
#pragma unroll
    for (int nt = 0; nt < 8; ++nt)
#pragma unroll
      for (int pt = 0; pt < 4; ++pt)
        acc[nt][pt] = MFMA(aB[nt], bfrB[pt], acc[nt][pt]);
    SB();
    // epilogue: bias (LDS) + swish -> bf16 pack -> Hs (in place; single wave,
    // ds ops are in-order per wave -> no barrier needed)
#pragma unroll
    for (int nt = 0; nt < 8; ++nt) {
      const f32x4 bv = *reinterpret_cast<const f32x4*>(bl + nt * 16 + lh * 4);
#pragma unroll
      for (int pt = 0; pt < 4; ++pt) {
        const uint2 wv = pack4(swish4(acc[nt][pt] + bv));
        *reinterpret_cast<uint2*>(Hs + ((wa0 + pt * 4096) ^ (nt << 5))) = wv;
      }
    }
  }

  // ================= final layer : [128 -> 2], weights already in aA =================
  {
    const float bl0 = bL[0], bl1 = bL[1];
#pragma unroll
    for (int pt = 0; pt < 4; ++pt) {
      f32x4 accL = {0.f, 0.f, 0.f, 0.f};
#pragma unroll
      for (int ks = 0; ks < 4; ++ks) {
        const bf16x8 bfr = LRD(Hs + ((va0 + pt * 4096) ^ (ks << 6)));
        accL = MFMA(aA[ks], bfr, accL);
      }
      if (lh == 0) {
        const int p = pt * 16 + lm;
        float2 o;
        o.x = accL[0] + bl0;
        o.y = accL[1] + bl1;
        *reinterpret_cast<float2*>(out + (size_t)(row0 + p) * 2) = o;
      }
    }
  }
}

extern "C" void kernel_launch(void* const* d_in, const int* in_sizes, int n_in,
                              void* d_out, int out_size, void* d_ws, size_t ws_size,
                              hipStream_t stream) {
  const float* X     = (const float*)d_in[0];
  const float* numin = (const float*)d_in[1];
  const float* numax = (const float*)d_in[2];
  const float* W0    = (const float*)d_in[3];
  const float* b0    = (const float*)d_in[4];
  const float* Wh    = (const float*)d_in[5];
  const float* bh    = (const float*)d_in[6];
  const float* WL    = (const float*)d_in[7];
  const float* bL    = (const float*)d_in[8];
  unsigned short* ws = (unsigned short*)d_ws;
  float* out = (float*)d_out;

  hipLaunchKernelGGL(prep_kernel, dim3(352), dim3(256), 0, stream, W0, Wh, WL, ws);
  hipLaunchKernelGGL(mlp_kernel, dim3(4096), dim3(64), 0, stream,
                     X, numin, numax, b0, bh, bL, ws, out);
}

// Round 17
// 76.716 us; speedup vs baseline: 1.0669x; 1.0235x over previous
//
#include <hip/hip_runtime.h>

typedef __bf16 bf16x8 __attribute__((ext_vector_type(8)));
typedef __bf16 bf16x2 __attribute__((ext_vector_type(2)));
typedef float  f32x4  __attribute__((ext_vector_type(4)));

// ws layout (bytes). All A-operand fragments lane-linear:
// one frag = 1024 B; lane l's 16 B at frag_base + l*16 (coalesced dwordx4).
//   WT0 : 8 frags   (nt 0..7, K=32 zero-padded)      [0      .. 8191  ]
//   WTH : 160 frags ((h*4+ks)*8 + nt)                [8192   .. 172031]
//   WLT : 8 frags   (ks 0..3 real, 4..7 zero pad)    [172032 .. 180223]
#define WS_WT0_B 0
#define WS_WTH_B 8192
#define WS_WLT_B 172032

__device__ __forceinline__ unsigned short f2b(float f) {
  return __builtin_bit_cast(unsigned short, (__bf16)f);
}

__global__ void prep_kernel(const float* __restrict__ W0,
                            const float* __restrict__ Wh,
                            const float* __restrict__ WL,
                            unsigned short* __restrict__ ws) {
  int i = blockIdx.x * 256 + threadIdx.x;   // ushort index == byte/2
  int l  = (i >> 3) & 63;                   // lane within frag
  int j  = i & 7;                           // element within lane's 8
  int lm = l & 15, lh = l >> 4;
  if (i < 4096) {                           // WT0
    int nt = i >> 9;
    int n = nt * 16 + lm, k = lh * 8 + j;
    ws[i] = f2b(k < 4 ? W0[k * 128 + n] : 0.f);
  } else if (i < 86016) {                   // WTH
    int t = i - 4096;
    int frag = t >> 9;                      // (h*4+ks)*8 + nt
    int nt = frag & 7, ks = (frag >> 3) & 3, h = frag >> 5;
    int n = nt * 16 + lm, k = ks * 32 + lh * 8 + j;
    ws[i] = f2b(Wh[(h * 128 + k) * 128 + n]);
  } else if (i < 90112) {                   // WLT (8 frags, 4 real + 4 zero)
    int t = i - 86016;
    int f = t >> 9;
    int k = (f & 3) * 32 + lh * 8 + j;
    ws[i] = f2b((f < 4 && lm < 2) ? WL[k * 2 + lm] : 0.f);
  }
}

// swish via exp2: u = z * -log2(e), e = 2^u, s = rcp(1+e), z*s.
__device__ __forceinline__ f32x4 swish4(f32x4 z) {
  const f32x4 u = z * (-1.44269504088896340736f);
  f32x4 e;
#if __has_builtin(__builtin_amdgcn_exp2f)
  e[0] = __builtin_amdgcn_exp2f(u[0]); e[1] = __builtin_amdgcn_exp2f(u[1]);
  e[2] = __builtin_amdgcn_exp2f(u[2]); e[3] = __builtin_amdgcn_exp2f(u[3]);
#else
  e[0] = __expf(u[0] * 0.6931471805599453f); e[1] = __expf(u[1] * 0.6931471805599453f);
  e[2] = __expf(u[2] * 0.6931471805599453f); e[3] = __expf(u[3] * 0.6931471805599453f);
#endif
  const f32x4 w = e + 1.f;
  f32x4 s;
  s[0] = __builtin_amdgcn_rcpf(w[0]); s[1] = __builtin_amdgcn_rcpf(w[1]);
  s[2] = __builtin_amdgcn_rcpf(w[2]); s[3] = __builtin_amdgcn_rcpf(w[3]);
  return z * s;
}

__device__ __forceinline__ uint2 pack4(f32x4 r) {   // v_cvt_pk_bf16_f32 path
  bf16x2 lo = {(__bf16)r[0], (__bf16)r[1]};
  bf16x2 hi = {(__bf16)r[2], (__bf16)r[3]};
  uint2 wv;
  wv.x = __builtin_bit_cast(unsigned int, lo);
  wv.y = __builtin_bit_cast(unsigned int, hi);
  return wv;
}

#define LRD(addr) __builtin_bit_cast(bf16x8, *reinterpret_cast<const uint4*>(addr))
#define MFMA(a, b, c) __builtin_amdgcn_mfma_f32_16x16x32_bf16((a), (b), (c), 0, 0, 0)

// Cooperative 8KB stage: 256 threads x 2 x 16B direct global->LDS.
// LDS dest must be linear per wave (base + lane*16) -> our frag layout is.
__device__ __forceinline__ void stage8k(const char* src, char* dst, int tid) {
  const int woff = (tid >> 6) * 1024;    // wave-uniform LDS base
#if __has_builtin(__builtin_amdgcn_global_load_lds)
  __builtin_amdgcn_global_load_lds(
      (const __attribute__((address_space(1))) unsigned int*)(src + tid * 16),
      (__attribute__((address_space(3))) unsigned int*)(dst + woff), 16, 0, 0);
  __builtin_amdgcn_global_load_lds(
      (const __attribute__((address_space(1))) unsigned int*)(src + 4096 + tid * 16),
      (__attribute__((address_space(3))) unsigned int*)(dst + 4096 + woff), 16, 0, 0);
#else
  const uint4 v0 = *reinterpret_cast<const uint4*>(src + tid * 16);
  const uint4 v1 = *reinterpret_cast<const uint4*>(src + 4096 + tid * 16);
  *reinterpret_cast<uint4*>(dst + tid * 16) = v0;
  *reinterpret_cast<uint4*>(dst + 4096 + tid * 16) = v1;
#endif
}

// 4 waves/block. Each wave owns 32 points privately (Hs strip, epilogue,
// B-frags); the weight stream is SHARED: staged cooperatively into LDS,
// double-buffered at ks (8KB) granularity, one phase of prefetch ahead.
// Phase = { issue stage(next) ; ds_read A-frags(cur) ; 16 MFMA ;
//           [epilogue at layer end] ; __syncthreads }.
// This is the empirical best of 6 structure families tried (R0-R16):
// private-stream (83.4us), counted-vmcnt (90), channel-split (83.7),
// 64pt-ILP (spills) — this one: 84.6us dispatch / 76.7us dur.
__launch_bounds__(256, 3)
__global__ void mlp_kernel(const float* __restrict__ X,
                           const float* __restrict__ nu_min_p,
                           const float* __restrict__ nu_max_p,
                           const float* __restrict__ b0,
                           const float* __restrict__ bh,
                           const float* __restrict__ bL,
                           const unsigned short* __restrict__ ws,
                           float* __restrict__ out) {
  __shared__ __align__(16) char smem[32768 + 16384 + 2560];
  const int tid  = threadIdx.x;
  const int lane = tid & 63, wave = tid >> 6;
  char* Hs  = smem + wave * 8192;          // private [32 pt][128 ch] strip
  char* wb0 = smem + 32768;                // shared weight buffers (8KB each)
  char* wb1 = smem + 40960;
  float* bias_lds = reinterpret_cast<float*>(smem + 49152);
  const int lm = lane & 15, lh = lane >> 4;
  const int row0 = blockIdx.x * 128 + wave * 32;
  const char* wsb = reinterpret_cast<const char*>(ws);
  const int xorm = (lm & 7) << 4;
  // rd(pt,ks) = va[pt] ^ (ks<<6); wr(nt,pt) = wa[pt] ^ (nt<<5)
  const int va0 = lm * 256 + ((lh * 16) ^ xorm);
  const int va1 = va0 + 4096;
  const int wa0 = lm * 256 + ((lh * 8) ^ xorm);
  const int wa1 = wa0 + 4096;

  // ---- prologue: stage L0 weights; bias cache; L0 bias regs; inputs ----
  stage8k(wsb + WS_WT0_B, wb0, tid);
  f32x4 bv0[8];
#pragma unroll
  for (int nt = 0; nt < 8; ++nt)
    bv0[nt] = *reinterpret_cast<const f32x4*>(b0 + nt * 16 + lh * 4);
#pragma unroll
  for (int i = 0; i < 3; ++i) {
    const int idx = i * 256 + tid;
    if (idx < 640) bias_lds[idx] = bh[idx];
  }
  if (lane < 32) {
    const float4 xv = reinterpret_cast<const float4*>(X)[row0 + lane];
    const float numin = nu_min_p[0], numax = nu_max_p[0];
    const float v0 = xv.x;
    const float v1 = xv.y;
    const float v2 = 2.f * xv.z - 1.f;
    const float v3 = 2.f * (xv.w - numin) / (numax - numin) - 1.f;
    uint4 c0;
    c0.x = (unsigned)f2b(v0) | ((unsigned)f2b(v1) << 16);
    c0.y = (unsigned)f2b(v2) | ((unsigned)f2b(v3) << 16);
    c0.z = 0u; c0.w = 0u;
    const uint4 z4 = make_uint4(0u, 0u, 0u, 0u);
    const int xr = (lane & 7) << 4;
    char* rp = Hs + lane * 256;
    *reinterpret_cast<uint4*>(rp + (0  ^ xr)) = c0;
    *reinterpret_cast<uint4*>(rp + (16 ^ xr)) = z4;
    *reinterpret_cast<uint4*>(rp + (32 ^ xr)) = z4;
    *reinterpret_cast<uint4*>(rp + (48 ^ xr)) = z4;
  }
  __syncthreads();

  f32x4 acc[8][2];
  bf16x8 aa[8];
  const f32x4 zero4 = {0.f, 0.f, 0.f, 0.f};

  // ---- L0 phase: read wb0 (K=32), stage h0/ks0 -> wb1, bias C-in ----
  stage8k(wsb + WS_WTH_B, wb1, tid);
#pragma unroll
  for (int nt = 0; nt < 8; ++nt) aa[nt] = LRD(wb0 + nt * 1024 + lane * 16);
  {
    const bf16x8 f0 = LRD(Hs + va0);
    const bf16x8 f1 = LRD(Hs + va1);
#pragma unroll
    for (int nt = 0; nt < 8; ++nt) {
      acc[nt][0] = MFMA(aa[nt], f0, bv0[nt]);
      acc[nt][1] = MFMA(aa[nt], f1, bv0[nt]);
    }
  }
#pragma unroll
  for (int nt = 0; nt < 8; ++nt) {
#pragma unroll
    for (int pt = 0; pt < 2; ++pt) {
      const uint2 wv = pack4(swish4(acc[nt][pt]));
      *reinterpret_cast<uint2*>(Hs + ((pt ? wa1 : wa0) ^ (nt << 5))) = wv;
    }
  }
  __syncthreads();

  // phase body: stage SRC -> SBUF, compute ks-slice from RBUF
#define HPHASE(RBUF, SBUF, SRC, KSOFF, FIRST)                              \
  do {                                                                     \
    stage8k((SRC), (SBUF), tid);                                           \
    _Pragma("unroll")                                                      \
    for (int nt = 0; nt < 8; ++nt) aa[nt] = LRD((RBUF) + nt * 1024 + lane * 16); \
    const bf16x8 f0 = LRD(Hs + (va0 ^ (KSOFF)));                           \
    const bf16x8 f1 = LRD(Hs + (va1 ^ (KSOFF)));                           \
    _Pragma("unroll")                                                      \
    for (int nt = 0; nt < 8; ++nt) {                                       \
      acc[nt][0] = MFMA(aa[nt], f0, (FIRST) ? zero4 : acc[nt][0]);         \
      acc[nt][1] = MFMA(aa[nt], f1, (FIRST) ? zero4 : acc[nt][1]);         \
    }                                                                      \
  } while (0)

  // ============ 5 hidden layers : 4 shared-stage phases each ============
#pragma unroll 1
  for (int h = 0; h < 5; ++h) {
    const char* wsrc = wsb + WS_WTH_B + h * 32768;
    const float* bl = bias_lds + h * 128;
    const char* nsrc = (h < 4) ? (wsrc + 32768) : (wsb + WS_WLT_B);

    HPHASE(wb1, wb0, wsrc + 8192,  0,   true);   // ks0 (stages ks1)
    __syncthreads();
    HPHASE(wb0, wb1, wsrc + 16384, 64,  false);  // ks1 (stages ks2)
    __syncthreads();
    HPHASE(wb1, wb0, wsrc + 24576, 128, false);  // ks2 (stages ks3)
    __syncthreads();
    HPHASE(wb0, wb1, nsrc,         192, false);  // ks3 (stages next/WLT)
    // epilogue before the barrier: covers the in-flight stage + absorbs skew
#pragma unroll
    for (int nt = 0; nt < 8; ++nt) {
      const f32x4 bv = *reinterpret_cast<const f32x4*>(bl + nt * 16 + lh * 4);
#pragma unroll
      for (int pt = 0; pt < 2; ++pt) {
        const uint2 wv = pack4(swish4(acc[nt][pt] + bv));
        *reinterpret_cast<uint2*>(Hs + ((pt ? wa1 : wa0) ^ (nt << 5))) = wv;
      }
    }
    __syncthreads();
  }

  // ================= final layer : [128 -> 2], weights in wb1 =================
  {
    const float bl0 = bL[0], bl1 = bL[1];
#pragma unroll
    for (int ks = 0; ks < 4; ++ks) aa[ks] = LRD(wb1 + ks * 1024 + lane * 16);
#pragma unroll
    for (int pt = 0; pt < 2; ++pt) {
      f32x4 accL = {0.f, 0.f, 0.f, 0.f};
#pragma unroll
      for (int ks = 0; ks < 4; ++ks) {
        const bf16x8 f = LRD(Hs + ((pt ? va1 : va0) ^ (ks << 6)));
        accL = MFMA(aa[ks], f, accL);
      }
      if (lh == 0) {
        const int p = pt * 16 + lm;
        float2 o;
        o.x = accL[0] + bl0;
        o.y = accL[1] + bl1;
        *reinterpret_cast<float2*>(out + (size_t)(row0 + p) * 2) = o;
      }
    }
  }
#undef HPHASE
}

extern "C" void kernel_launch(void* const* d_in, const int* in_sizes, int n_in,
                              void* d_out, int out_size, void* d_ws, size_t ws_size,
                              hipStream_t stream) {
  const float* X     = (const float*)d_in[0];
  const float* numin = (const float*)d_in[1];
  const float* numax = (const float*)d_in[2];
  const float* W0    = (const float*)d_in[3];
  const float* b0    = (const float*)d_in[4];
  const float* Wh    = (const float*)d_in[5];
  const float* bh    = (const float*)d_in[6];
  const float* WL    = (const float*)d_in[7];
  const float* bL    = (const float*)d_in[8];
  unsigned short* ws = (unsigned short*)d_ws;
  float* out = (float*)d_out;

  hipLaunchKernelGGL(prep_kernel, dim3(352), dim3(256), 0, stream, W0, Wh, WL, ws);
  hipLaunchKernelGGL(mlp_kernel, dim3(2048), dim3(256), 0, stream,
                     X, numin, numax, b0, bh, bL, ws, out);
}